// Round 8
// baseline (208.187 us; speedup 1.0000x reference)
//
#include <hip/hip_runtime.h>
#include <hip/hip_bf16.h>

typedef unsigned short u16;
typedef unsigned int u32;

#define TT 192
#define BB 2
#define HH 8
#define DD 64
#define CC 512
#define MM (BB*TT)   // 384

// ws layout (u16 elements): Q,K0,K1,V0,V1 each [bh][t][d], then ATT [m][c]
#define TSZ   ((size_t)MM * CC)
#define OFF_ATT (5 * TSZ)

typedef short bf16x8 __attribute__((ext_vector_type(8)));
typedef float f32x4  __attribute__((ext_vector_type(4)));

union FragU { uint4 u; bf16x8 b; };

__device__ __forceinline__ float bf2f(u16 u) {
    return __uint_as_float(((u32)u) << 16);
}
__device__ __forceinline__ u16 f2bf(float f) {
    u32 u = __float_as_uint(f);
    u32 r = u + 0x7FFFu + ((u >> 16) & 1u);   // RNE
    return (u16)(r >> 16);
}
// pack hi16(a),hi16(b) -> one u32 (truncation round; bias cancels in P/Z)
__device__ __forceinline__ u32 trunc_pk(u32 b_hi, u32 a_lo) {
    return __builtin_amdgcn_perm(b_hi, a_lo, 0x07060302u);
}

// dtype detect: 1 load + ballot. bf16 data => low u16 exponent near 127.
__device__ __forceinline__ u32 detect_bf16_fast(const u32* __restrict__ x) {
    const int lane = threadIdx.x & 63;
    u32 v = x[lane & 31];
    u32 e = (v >> 7) & 0xFF;
    unsigned long long m = __ballot(e >= 113 && e <= 133);
    return (__popcll(m) >= 32) ? 1u : 0u;
}

__device__ __forceinline__ FragU ldfrag(const void* __restrict__ base, size_t off, u32 fl) {
    FragU f;
    if (fl) {
        f.u = *(const uint4*)((const u16*)base + off);
    } else {
        const float* s = (const float*)base + off;
        float4 a = *(const float4*)s;
        float4 b = *(const float4*)(s + 4);
        u32 p0 = (u32)f2bf(a.x) | ((u32)f2bf(a.y) << 16);
        u32 p1 = (u32)f2bf(a.z) | ((u32)f2bf(a.w) << 16);
        u32 p2 = (u32)f2bf(b.x) | ((u32)f2bf(b.y) << 16);
        u32 p3 = (u32)f2bf(b.z) | ((u32)f2bf(b.w) << 16);
        f.u = make_uint4(p0, p1, p2, p3);
    }
    return f;
}

// ---------------------------------------------------------------------------
// MFMA projection GEMM: out[m,n] = sum_k A[m,k]*W[n,k] + bias[n]
// 64x64 tile, 4 waves, frags b128 from global, 2-stage register double-buffer.
// ---------------------------------------------------------------------------
__device__ __forceinline__ void proj_mfma(const void* __restrict__ A, u32 aFl,
                                          const void* __restrict__ W,
                                          const void* __restrict__ bias, u32 wFl,
                                          void* __restrict__ out, int headperm, u32 outFl) {
    const int tid = threadIdx.x;
    const int w = tid >> 6, lane = tid & 63;
    const int quad = lane >> 4, li = lane & 15;
    const int mb = blockIdx.y * 64, nb = blockIdx.x * 64;

    f32x4 acc[4];
#pragma unroll
    for (int ct = 0; ct < 4; ct++) acc[ct] = (f32x4){0.f, 0.f, 0.f, 0.f};

    if (aFl && wFl) {
        const u16* arow = (const u16*)A + (size_t)(mb + w * 16 + li) * CC + quad * 8;
        const u16* wrow[4];
#pragma unroll
        for (int ct = 0; ct < 4; ct++)
            wrow[ct] = (const u16*)W + (size_t)(nb + ct * 16 + li) * CC + quad * 8;

        FragU af[2], wf[2][4];
        af[0].u = *(const uint4*)(arow);
#pragma unroll
        for (int ct = 0; ct < 4; ct++) wf[0][ct].u = *(const uint4*)(wrow[ct]);

#pragma unroll
        for (int i = 0; i < 16; i++) {
            const int s = i & 1;
            if (i < 15) {
                const int kb = (i + 1) * 32;
                af[s ^ 1].u = *(const uint4*)(arow + kb);
#pragma unroll
                for (int ct = 0; ct < 4; ct++) wf[s ^ 1][ct].u = *(const uint4*)(wrow[ct] + kb);
            }
#pragma unroll
            for (int ct = 0; ct < 4; ct++)
                acc[ct] = __builtin_amdgcn_mfma_f32_16x16x32_bf16(af[s].b, wf[s][ct].b, acc[ct], 0, 0, 0);
        }
    } else {
        const size_t aoff = (size_t)(mb + w * 16 + li) * CC;
#pragma unroll 4
        for (int kb = 0; kb < CC; kb += 32) {
            FragU af = ldfrag(A, aoff + kb + quad * 8, aFl);
#pragma unroll
            for (int ct = 0; ct < 4; ct++) {
                FragU bf_ = ldfrag(W, (size_t)(nb + ct * 16 + li) * CC + kb + quad * 8, wFl);
                acc[ct] = __builtin_amdgcn_mfma_f32_16x16x32_bf16(af.b, bf_.b, acc[ct], 0, 0, 0);
            }
        }
    }

#pragma unroll
    for (int ct = 0; ct < 4; ct++) {
        const int n = nb + ct * 16 + li;
        const float bv = wFl ? bf2f(((const u16*)bias)[n]) : ((const float*)bias)[n];
#pragma unroll
        for (int r = 0; r < 4; r++) {
            const int m = mb + w * 16 + quad * 4 + r;
            const float v = acc[ct][r] + bv;
            if (headperm) {
                const int b = (m >= TT) ? 1 : 0;
                const int tloc = m - b * TT;
                ((u16*)out)[((size_t)(b * HH + (n >> 6)) * TT + tloc) * DD + (n & 63)] = f2bf(v);
            } else {
                if (outFl) ((u16*)out)[(size_t)m * CC + n] = f2bf(v);
                else       ((float*)out)[(size_t)m * CC + n] = v;
            }
        }
    }
}

__global__ __launch_bounds__(256) void proj5_kernel(
    const void* __restrict__ x,
    const void* __restrict__ Wq,  const void* __restrict__ bq,
    const void* __restrict__ Wk0, const void* __restrict__ bk0,
    const void* __restrict__ Wk1, const void* __restrict__ bk1,
    const void* __restrict__ Wv0, const void* __restrict__ bv0,
    const void* __restrict__ Wv1, const void* __restrict__ bv1,
    u16* __restrict__ ws16) {
    const u32 fl = detect_bf16_fast((const u32*)x);
    const int z = blockIdx.z;
    const void* W; const void* bi;
    switch (z) {
        case 0:  W = Wq;  bi = bq;  break;
        case 1:  W = Wk0; bi = bk0; break;
        case 2:  W = Wk1; bi = bk1; break;
        case 3:  W = Wv0; bi = bv0; break;
        default: W = Wv1; bi = bv1; break;
    }
    proj_mfma(x, fl, W, bi, fl, (void*)(ws16 + (size_t)z * TSZ), 1, 1u);
}

__global__ __launch_bounds__(256) void projo_kernel(const u16* __restrict__ ws16,
                                                    const void* __restrict__ Wo,
                                                    const void* __restrict__ bo,
                                                    void* __restrict__ out,
                                                    const void* __restrict__ xorig) {
    const u32 fl = detect_bf16_fast((const u32*)xorig);
    proj_mfma(ws16 + OFF_ATT, 1u, Wo, bo, fl, out, 0, fl);
}

// ---------------------------------------------------------------------------
// MFMA attention. Block = (b,h,k), 4 waves; wave owns 48 l-rows.
// GEMM1 (transposed): S^T[m,l] = sum_d k1[m,d]*(scl*q[d]*k0[l,d]),
//   k1-frags b128 from global. exp2 -> P bf16 (trunc pack) -> 1 ds_write_b64.
// GEMM2: W'[l,d] += P[l,m]*v1[m,d]; B = v1 in NATURAL [m][d] layout read
//   straight from global (reg j = v1[mt*32+quad*8+j][16cd+li]) -- no LDS
//   transpose, no staging barrier. Z[l] via mfma(P, ones).
// epilogue: out[d] = sum_l v0[l,d] * W'[l,d] / Z[l], v0 from global.
// LDS 15360B (P only; osum overlays after barrier) -> occupancy cap lifted.
// NOTE: no min-waves bound (round 5: (256,4) => 64 VGPR cap => spills);
//       no m-loop unroll pragma (round 7: unroll 2 => 70->80us).
// ---------------------------------------------------------------------------
__global__ __launch_bounds__(256) void attn_kernel(u16* __restrict__ ws16) {
    __shared__ __align__(16) u16 smem[7680];   // 15360 B = P [192 l][40]
    const int tid = threadIdx.x;
    const int w = tid >> 6, lane = tid & 63;
    const int quad = lane >> 4, li = lane & 15;
    const int k = blockIdx.x, bh = blockIdx.y;

    const u16* qg  = ws16 + ((size_t)bh * TT + k) * DD;
    const u16* k0g = ws16 + TSZ     + (size_t)bh * TT * DD;
    const u16* k1g = ws16 + 2 * TSZ + (size_t)bh * TT * DD;
    const u16* v0g = ws16 + 3 * TSZ + (size_t)bh * TT * DD;
    const u16* v1g = ws16 + 4 * TSZ + (size_t)bh * TT * DD;

    // ---- afr (B-operand of GEMM1): a[l,d] = bf16_trunc(scl*q[d]*k0[l,d]) ----
    FragU afr[3][2];
#pragma unroll
    for (int kk = 0; kk < 2; kk++) {
        uint4 qu = *(const uint4*)(qg + kk * 32 + quad * 8);
        u16 qv[8]; *(uint4*)qv = qu;
        float qf[8];
#pragma unroll
        for (int j = 0; j < 8; j++) qf[j] = bf2f(qv[j]) * 0.18033688f;  // 0.125*log2e
#pragma unroll
        for (int rt = 0; rt < 3; rt++) {
            uint4 ku = *(const uint4*)(k0g + (size_t)(w * 48 + rt * 16 + li) * DD + kk * 32 + quad * 8);
            u16 kv[8]; *(uint4*)kv = ku;
            u32 pk[4];
#pragma unroll
            for (int p = 0; p < 4; p++) {
                u32 lo = __float_as_uint(qf[2 * p] * bf2f(kv[2 * p]));
                u32 hi = __float_as_uint(qf[2 * p + 1] * bf2f(kv[2 * p + 1]));
                pk[p] = trunc_pk(hi, lo);
            }
            afr[rt][kk].u = make_uint4(pk[0], pk[1], pk[2], pk[3]);
        }
    }

    FragU ones;
    ones.u = make_uint4(0x3F803F80u, 0x3F803F80u, 0x3F803F80u, 0x3F803F80u);

    f32x4 Wacc[3][4], Zacc[3];
#pragma unroll
    for (int rt = 0; rt < 3; rt++) {
        Zacc[rt] = (f32x4){0.f, 0.f, 0.f, 0.f};
#pragma unroll
        for (int cd = 0; cd < 4; cd++) Wacc[rt][cd] = (f32x4){0.f, 0.f, 0.f, 0.f};
    }

    // ---- m-tile loop (6 x 32), fully barrier-free (P rows wave-private) ----
    for (int mt = 0; mt < 6; mt++) {
        // GEMM1 (transposed) + exp2 + truncation-packed b64 P-write
#pragma unroll
        for (int ct = 0; ct < 2; ct++) {
            const u16* krow = k1g + (size_t)(mt * 32 + ct * 16 + li) * DD + quad * 8;
            FragU kf0, kf1;
            kf0.u = *(const uint4*)(krow);
            kf1.u = *(const uint4*)(krow + 32);
#pragma unroll
            for (int rt = 0; rt < 3; rt++) {
                f32x4 acc = (f32x4){0.f, 0.f, 0.f, 0.f};
                acc = __builtin_amdgcn_mfma_f32_16x16x32_bf16(kf0.b, afr[rt][0].b, acc, 0, 0, 0);
                acc = __builtin_amdgcn_mfma_f32_16x16x32_bf16(kf1.b, afr[rt][1].b, acc, 0, 0, 0);
                u32 lo = trunc_pk(__float_as_uint(exp2f(acc[1])), __float_as_uint(exp2f(acc[0])));
                u32 hi = trunc_pk(__float_as_uint(exp2f(acc[3])), __float_as_uint(exp2f(acc[2])));
                const int l = w * 48 + rt * 16 + li;
                *(uint2*)(smem + l * 40 + ct * 16 + quad * 4) = make_uint2(lo, hi);
            }
        }
        // B-frags of GEMM2: v1 natural layout straight from global (L1/L2-hot)
        FragU b2[4];
        {
            const u16* vrow = v1g + (size_t)(mt * 32 + quad * 8) * DD + li;
#pragma unroll
            for (int cd = 0; cd < 4; cd++) {
                const u16* vp = vrow + cd * 16;
                u32 p0 = (u32)vp[0] | ((u32)vp[DD] << 16);
                u32 p1 = (u32)vp[2 * DD] | ((u32)vp[3 * DD] << 16);
                u32 p2 = (u32)vp[4 * DD] | ((u32)vp[5 * DD] << 16);
                u32 p3 = (u32)vp[6 * DD] | ((u32)vp[7 * DD] << 16);
                b2[cd].u = make_uint4(p0, p1, p2, p3);
            }
        }
        // GEMM2 + Z on MFMA pipe
        FragU a2[3];
#pragma unroll
        for (int rt = 0; rt < 3; rt++)
            a2[rt].u = *(const uint4*)(smem + (w * 48 + rt * 16 + li) * 40 + quad * 8);
#pragma unroll
        for (int rt = 0; rt < 3; rt++) {
            Zacc[rt] = __builtin_amdgcn_mfma_f32_16x16x32_bf16(a2[rt].b, ones.b, Zacc[rt], 0, 0, 0);
#pragma unroll
            for (int cd = 0; cd < 4; cd++)
                Wacc[rt][cd] = __builtin_amdgcn_mfma_f32_16x16x32_bf16(a2[rt].b, b2[cd].b, Wacc[rt][cd], 0, 0, 0);
        }
    }

    __syncthreads();   // all waves done with P (osum overlays P region)

    // ---- epilogue: v0 straight from global, per-rt to cap live VGPRs ----
    float op[4] = {0.f, 0.f, 0.f, 0.f};
#pragma unroll
    for (int rt = 0; rt < 3; rt++) {
        float v0v[4][4];
#pragma unroll
        for (int r = 0; r < 4; r++) {
            const int l = w * 48 + rt * 16 + quad * 4 + r;
#pragma unroll
            for (int cd = 0; cd < 4; cd++)
                v0v[r][cd] = bf2f(v0g[(size_t)l * DD + cd * 16 + li]);
        }
#pragma unroll
        for (int r = 0; r < 4; r++) {
            const float iv = 1.f / Zacc[rt][r];
#pragma unroll
            for (int cd = 0; cd < 4; cd++)
                op[cd] = fmaf(v0v[r][cd] * iv, Wacc[rt][cd][r], op[cd]);
        }
    }
#pragma unroll
    for (int cd = 0; cd < 4; cd++) {
        op[cd] += __shfl_xor(op[cd], 16);
        op[cd] += __shfl_xor(op[cd], 32);
    }
    float* osum = (float*)smem;
    if (quad == 0) {
#pragma unroll
        for (int cd = 0; cd < 4; cd++) osum[w * 64 + cd * 16 + li] = op[cd];
    }
    __syncthreads();
    if (tid < DD) {
        const float o = osum[tid] + osum[64 + tid] + osum[128 + tid] + osum[192 + tid];
        const int b = bh >> 3, h = bh & 7;
        u16* ATT = ws16 + OFF_ATT;
        ATT[((size_t)(b * TT + k)) * CC + h * DD + tid] = f2bf(o);
    }
}

extern "C" void kernel_launch(void* const* d_in, const int* in_sizes, int n_in,
                              void* d_out, int out_size, void* d_ws, size_t ws_size,
                              hipStream_t stream) {
    u16* ws16 = (u16*)d_ws;

    dim3 gp(CC / 64, MM / 64, 5);   // 8 x 6 x 5
    proj5_kernel<<<gp, 256, 0, stream>>>(
        d_in[0], d_in[1], d_in[2], d_in[3], d_in[4], d_in[5], d_in[6],
        d_in[7], d_in[8], d_in[9], d_in[10], ws16);

    dim3 ga(TT, BB * HH);           // 192 x 16
    attn_kernel<<<ga, 256, 0, stream>>>(ws16);

    dim3 go(CC / 64, MM / 64, 1);   // 8 x 6
    projo_kernel<<<go, 256, 0, stream>>>(ws16, d_in[11], d_in[12], d_out, d_in[0]);
}

// Round 9
// 164.998 us; speedup vs baseline: 1.2617x; 1.2617x over previous
//
#include <hip/hip_runtime.h>
#include <hip/hip_bf16.h>

typedef unsigned short u16;
typedef unsigned int u32;

#define TT 192
#define BB 2
#define HH 8
#define DD 64
#define CC 512
#define MM (BB*TT)   // 384

// ws layout (u16 elements): Q,K0,K1,V0,V1 each [bh][t][d], then ATT [m][c]
#define TSZ   ((size_t)MM * CC)
#define OFF_ATT (5 * TSZ)

typedef short bf16x8 __attribute__((ext_vector_type(8)));
typedef float f32x4  __attribute__((ext_vector_type(4)));

union FragU { uint4 u; bf16x8 b; };

__device__ __forceinline__ float bf2f(u16 u) {
    return __uint_as_float(((u32)u) << 16);
}
__device__ __forceinline__ u16 f2bf(float f) {
    u32 u = __float_as_uint(f);
    u32 r = u + 0x7FFFu + ((u >> 16) & 1u);   // RNE
    return (u16)(r >> 16);
}
// pack hi16(a),hi16(b) -> one u32 (truncation round; bias cancels in P/Z)
__device__ __forceinline__ u32 trunc_pk(u32 b_hi, u32 a_lo) {
    return __builtin_amdgcn_perm(b_hi, a_lo, 0x07060302u);
}

// dtype detect: 1 load + ballot. bf16 data => low u16 exponent near 127.
__device__ __forceinline__ u32 detect_bf16_fast(const u32* __restrict__ x) {
    const int lane = threadIdx.x & 63;
    u32 v = x[lane & 31];
    u32 e = (v >> 7) & 0xFF;
    unsigned long long m = __ballot(e >= 113 && e <= 133);
    return (__popcll(m) >= 32) ? 1u : 0u;
}

// dtype-aware 16-element load (two uint4 of packed bf16)
__device__ __forceinline__ void ld16(const void* __restrict__ base, size_t off, u32 fl,
                                     uint4& lo, uint4& hi) {
    if (fl) {
        const uint4* p = (const uint4*)((const u16*)base + off);
        lo = p[0]; hi = p[1];
    } else {
        const float* s = (const float*)base + off;
        float4 f0 = *(const float4*)(s);
        float4 f1 = *(const float4*)(s + 4);
        float4 f2 = *(const float4*)(s + 8);
        float4 f3 = *(const float4*)(s + 12);
        lo = make_uint4((u32)f2bf(f0.x) | ((u32)f2bf(f0.y) << 16),
                        (u32)f2bf(f0.z) | ((u32)f2bf(f0.w) << 16),
                        (u32)f2bf(f1.x) | ((u32)f2bf(f1.y) << 16),
                        (u32)f2bf(f1.z) | ((u32)f2bf(f1.w) << 16));
        hi = make_uint4((u32)f2bf(f2.x) | ((u32)f2bf(f2.y) << 16),
                        (u32)f2bf(f2.z) | ((u32)f2bf(f2.w) << 16),
                        (u32)f2bf(f3.x) | ((u32)f2bf(f3.y) << 16),
                        (u32)f2bf(f3.z) | ((u32)f2bf(f3.w) << 16));
    }
}

// ---------------------------------------------------------------------------
// LDS-staged MFMA projection GEMM: out[m,n] = sum_k A[m,k]*W[n,k] + bias[n]
// 64x64 tile, 4 waves, BK=64 (8 steps). Staging loads are 128B-contiguous
// per 4 lanes (coalesced; the r5-r8 direct-global frag loads split into 64
// cache lines per instruction and made the projections ~10x too slow).
// LDS tiles stride 72 u16 -> 2-way bank aliasing only. Register prefetch of
// step k+1 issued between the store-barrier and compute.
// ---------------------------------------------------------------------------
__device__ __forceinline__ void proj_lds(const void* __restrict__ A, u32 aFl,
                                         const void* __restrict__ W,
                                         const void* __restrict__ bias, u32 wFl,
                                         void* __restrict__ out, int headperm, u32 outFl) {
    __shared__ __align__(16) u16 As[64][72];
    __shared__ __align__(16) u16 Ws[64][72];
    const int tid = threadIdx.x;
    const int w = tid >> 6, lane = tid & 63;
    const int quad = lane >> 4, li = lane & 15;
    const int mb = blockIdx.y * 64, nb = blockIdx.x * 64;

    const int r = tid >> 2;            // 0..63: tile row this thread stages
    const int c = (tid & 3) * 16;      // 0,16,32,48: k-chunk (u16 units)

    const size_t abase = (size_t)(mb + r) * CC + c;
    const size_t wbase = (size_t)(nb + r) * CC + c;

    f32x4 acc[4];
#pragma unroll
    for (int ct = 0; ct < 4; ct++) acc[ct] = (f32x4){0.f, 0.f, 0.f, 0.f};

    uint4 a0, a1, w0, w1;
    ld16(A, abase, aFl, a0, a1);
    ld16(W, wbase, wFl, w0, w1);

#pragma unroll
    for (int step = 0; step < 8; step++) {
        *(uint4*)&As[r][c] = a0; *(uint4*)&As[r][c + 8] = a1;
        *(uint4*)&Ws[r][c] = w0; *(uint4*)&Ws[r][c + 8] = w1;
        __syncthreads();
        if (step < 7) {
            const int kb = (step + 1) * 64;
            ld16(A, abase + kb, aFl, a0, a1);
            ld16(W, wbase + kb, wFl, w0, w1);
        }
#pragma unroll
        for (int kk = 0; kk < 2; kk++) {
            FragU af; af.u = *(const uint4*)&As[w * 16 + li][kk * 32 + quad * 8];
#pragma unroll
            for (int ct = 0; ct < 4; ct++) {
                FragU wf; wf.u = *(const uint4*)&Ws[ct * 16 + li][kk * 32 + quad * 8];
                acc[ct] = __builtin_amdgcn_mfma_f32_16x16x32_bf16(af.b, wf.b, acc[ct], 0, 0, 0);
            }
        }
        __syncthreads();
    }

#pragma unroll
    for (int ct = 0; ct < 4; ct++) {
        const int n = nb + ct * 16 + li;
        const float bv = wFl ? bf2f(((const u16*)bias)[n]) : ((const float*)bias)[n];
#pragma unroll
        for (int rr = 0; rr < 4; rr++) {
            const int m = mb + w * 16 + quad * 4 + rr;
            const float v = acc[ct][rr] + bv;
            if (headperm) {
                const int b = (m >= TT) ? 1 : 0;
                const int tloc = m - b * TT;
                ((u16*)out)[((size_t)(b * HH + (n >> 6)) * TT + tloc) * DD + (n & 63)] = f2bf(v);
            } else {
                if (outFl) ((u16*)out)[(size_t)m * CC + n] = f2bf(v);
                else       ((float*)out)[(size_t)m * CC + n] = v;
            }
        }
    }
}

__global__ __launch_bounds__(256) void proj5_kernel(
    const void* __restrict__ x,
    const void* __restrict__ Wq,  const void* __restrict__ bq,
    const void* __restrict__ Wk0, const void* __restrict__ bk0,
    const void* __restrict__ Wk1, const void* __restrict__ bk1,
    const void* __restrict__ Wv0, const void* __restrict__ bv0,
    const void* __restrict__ Wv1, const void* __restrict__ bv1,
    u16* __restrict__ ws16) {
    const u32 fl = detect_bf16_fast((const u32*)x);
    const int z = blockIdx.z;
    const void* W; const void* bi;
    switch (z) {
        case 0:  W = Wq;  bi = bq;  break;
        case 1:  W = Wk0; bi = bk0; break;
        case 2:  W = Wk1; bi = bk1; break;
        case 3:  W = Wv0; bi = bv0; break;
        default: W = Wv1; bi = bv1; break;
    }
    proj_lds(x, fl, W, bi, fl, (void*)(ws16 + (size_t)z * TSZ), 1, 1u);
}

__global__ __launch_bounds__(256) void projo_kernel(const u16* __restrict__ ws16,
                                                    const void* __restrict__ Wo,
                                                    const void* __restrict__ bo,
                                                    void* __restrict__ out,
                                                    const void* __restrict__ xorig) {
    const u32 fl = detect_bf16_fast((const u32*)xorig);
    proj_lds(ws16 + OFF_ATT, 1u, Wo, bo, fl, out, 0, fl);
}

// ---------------------------------------------------------------------------
// MFMA attention (r6 structure + r7 trunc-pack; r7 unroll2 and r8
// v1-from-global both regressed and are reverted).
// Block = (b,h,k), 4 waves; wave owns 48 l-rows.
// GEMM1 (transposed): S^T[m,l] = sum_d k1[m,d]*(scl*q[d]*k0[l,d]),
//   k1-frags b128 from global. exp2 -> P bf16 (trunc pack) -> 1 ds_write_b64.
// GEMM2: W'[l,d] += P[l,m]*v1[m,d] via v1^T staged swizzled in LDS;
//   Z[l] via mfma(P, ones).
// epilogue: out[d] = sum_l v0[l,d] * W'[l,d] / Z[l], v0 from global.
// LDS 40960B: v1t [64 d][200] swz @0 | P [192 l][40] @12800
// NOTE: no min-waves bound (r5: (256,4) => 64 VGPR cap => spills).
// ---------------------------------------------------------------------------
#define LP_P  12800
#define LP_OS 12800

__global__ __launch_bounds__(256) void attn_kernel(u16* __restrict__ ws16) {
    __shared__ __align__(16) u16 smem[20480];   // 40960 B
    const int tid = threadIdx.x;
    const int w = tid >> 6, lane = tid & 63;
    const int quad = lane >> 4, li = lane & 15;
    const int k = blockIdx.x, bh = blockIdx.y;

    const u16* qg  = ws16 + ((size_t)bh * TT + k) * DD;
    const u16* k0g = ws16 + TSZ     + (size_t)bh * TT * DD;
    const u16* k1g = ws16 + 2 * TSZ + (size_t)bh * TT * DD;
    const u16* v0g = ws16 + 3 * TSZ + (size_t)bh * TT * DD;
    const u16* v1g = ws16 + 4 * TSZ + (size_t)bh * TT * DD;

    // ---- stage v1^T (stride 200, swz (m>>3)^(d>>3); stores 2-way max) ----
#pragma unroll
    for (int it = 0; it < 6; it++) {
        const int flat = (it * 256 + tid) * 8;
        const int row = flat >> 6, c0 = flat & 63;   // row=m, c0=d base
        uint4 b = *(const uint4*)(v1g + flat);
        u16 vb[8]; *(uint4*)vb = b;
        const int swz = (((row >> 3) ^ (c0 >> 3)) << 3) | (row & 7);
#pragma unroll
        for (int j = 0; j < 8; j++)
            smem[(c0 + j) * 200 + swz] = vb[j];
    }

    // ---- afr (B-operand): a[l,d] = bf16_trunc(scl*q[d]*k0[l,d]) ----
    FragU afr[3][2];
#pragma unroll
    for (int kk = 0; kk < 2; kk++) {
        uint4 qu = *(const uint4*)(qg + kk * 32 + quad * 8);
        u16 qv[8]; *(uint4*)qv = qu;
        float qf[8];
#pragma unroll
        for (int j = 0; j < 8; j++) qf[j] = bf2f(qv[j]) * 0.18033688f;  // 0.125*log2e
#pragma unroll
        for (int rt = 0; rt < 3; rt++) {
            uint4 ku = *(const uint4*)(k0g + (size_t)(w * 48 + rt * 16 + li) * DD + kk * 32 + quad * 8);
            u16 kv[8]; *(uint4*)kv = ku;
            u32 pk[4];
#pragma unroll
            for (int p = 0; p < 4; p++) {
                u32 lo = __float_as_uint(qf[2 * p] * bf2f(kv[2 * p]));
                u32 hi = __float_as_uint(qf[2 * p + 1] * bf2f(kv[2 * p + 1]));
                pk[p] = trunc_pk(hi, lo);
            }
            afr[rt][kk].u = make_uint4(pk[0], pk[1], pk[2], pk[3]);
        }
    }

    FragU ones;
    ones.u = make_uint4(0x3F803F80u, 0x3F803F80u, 0x3F803F80u, 0x3F803F80u);

    f32x4 Wacc[3][4], Zacc[3];
#pragma unroll
    for (int rt = 0; rt < 3; rt++) {
        Zacc[rt] = (f32x4){0.f, 0.f, 0.f, 0.f};
#pragma unroll
        for (int cd = 0; cd < 4; cd++) Wacc[rt][cd] = (f32x4){0.f, 0.f, 0.f, 0.f};
    }

    __syncthreads();   // v1t staged

    // ---- m-tile loop (6 x 32), barrier-free (P rows wave-private) ----
    for (int mt = 0; mt < 6; mt++) {
        // GEMM1 (transposed) + exp2 + truncation-packed b64 P-write
#pragma unroll
        for (int ct = 0; ct < 2; ct++) {
            const u16* krow = k1g + (size_t)(mt * 32 + ct * 16 + li) * DD + quad * 8;
            FragU kf0, kf1;
            kf0.u = *(const uint4*)(krow);
            kf1.u = *(const uint4*)(krow + 32);
#pragma unroll
            for (int rt = 0; rt < 3; rt++) {
                f32x4 acc = (f32x4){0.f, 0.f, 0.f, 0.f};
                acc = __builtin_amdgcn_mfma_f32_16x16x32_bf16(kf0.b, afr[rt][0].b, acc, 0, 0, 0);
                acc = __builtin_amdgcn_mfma_f32_16x16x32_bf16(kf1.b, afr[rt][1].b, acc, 0, 0, 0);
                u32 lo = trunc_pk(__float_as_uint(exp2f(acc[1])), __float_as_uint(exp2f(acc[0])));
                u32 hi = trunc_pk(__float_as_uint(exp2f(acc[3])), __float_as_uint(exp2f(acc[2])));
                const int l = w * 48 + rt * 16 + li;
                *(uint2*)(smem + LP_P + l * 40 + ct * 16 + quad * 4) = make_uint2(lo, hi);
            }
        }
        // GEMM2 + Z on MFMA pipe (B-frags b128 from swizzled v1t)
        FragU a2[3], b2[4];
#pragma unroll
        for (int rt = 0; rt < 3; rt++)
            a2[rt].u = *(const uint4*)(smem + LP_P + (w * 48 + rt * 16 + li) * 40 + quad * 8);
#pragma unroll
        for (int cd = 0; cd < 4; cd++) {
            const int d = cd * 16 + li;
            b2[cd].u = *(const uint4*)(smem + d * 200 + (((mt * 4 + quad) ^ (d >> 3)) << 3));
        }
#pragma unroll
        for (int rt = 0; rt < 3; rt++) {
            Zacc[rt] = __builtin_amdgcn_mfma_f32_16x16x32_bf16(a2[rt].b, ones.b, Zacc[rt], 0, 0, 0);
#pragma unroll
            for (int cd = 0; cd < 4; cd++)
                Wacc[rt][cd] = __builtin_amdgcn_mfma_f32_16x16x32_bf16(a2[rt].b, b2[cd].b, Wacc[rt][cd], 0, 0, 0);
        }
    }

    __syncthreads();   // all waves done with P/v1t (osum overlays P region)

    // ---- epilogue: v0 straight from global, per-rt to cap live VGPRs ----
    float op[4] = {0.f, 0.f, 0.f, 0.f};
#pragma unroll
    for (int rt = 0; rt < 3; rt++) {
        float v0v[4][4];
#pragma unroll
        for (int r = 0; r < 4; r++) {
            const int l = w * 48 + rt * 16 + quad * 4 + r;
#pragma unroll
            for (int cd = 0; cd < 4; cd++)
                v0v[r][cd] = bf2f(v0g[(size_t)l * DD + cd * 16 + li]);
        }
#pragma unroll
        for (int r = 0; r < 4; r++) {
            const float iv = 1.f / Zacc[rt][r];
#pragma unroll
            for (int cd = 0; cd < 4; cd++)
                op[cd] = fmaf(v0v[r][cd] * iv, Wacc[rt][cd][r], op[cd]);
        }
    }
#pragma unroll
    for (int cd = 0; cd < 4; cd++) {
        op[cd] += __shfl_xor(op[cd], 16);
        op[cd] += __shfl_xor(op[cd], 32);
    }
    float* osum = (float*)(smem + LP_OS);
    if (quad == 0) {
#pragma unroll
        for (int cd = 0; cd < 4; cd++) osum[w * 64 + cd * 16 + li] = op[cd];
    }
    __syncthreads();
    if (tid < DD) {
        const float o = osum[tid] + osum[64 + tid] + osum[128 + tid] + osum[192 + tid];
        const int b = bh >> 3, h = bh & 7;
        u16* ATT = ws16 + OFF_ATT;
        ATT[((size_t)(b * TT + k)) * CC + h * DD + tid] = f2bf(o);
    }
}

extern "C" void kernel_launch(void* const* d_in, const int* in_sizes, int n_in,
                              void* d_out, int out_size, void* d_ws, size_t ws_size,
                              hipStream_t stream) {
    u16* ws16 = (u16*)d_ws;

    dim3 gp(CC / 64, MM / 64, 5);   // 8 x 6 x 5
    proj5_kernel<<<gp, 256, 0, stream>>>(
        d_in[0], d_in[1], d_in[2], d_in[3], d_in[4], d_in[5], d_in[6],
        d_in[7], d_in[8], d_in[9], d_in[10], ws16);

    dim3 ga(TT, BB * HH);           // 192 x 16
    attn_kernel<<<ga, 256, 0, stream>>>(ws16);

    dim3 go(CC / 64, MM / 64, 1);   // 8 x 6
    projo_kernel<<<go, 256, 0, stream>>>(ws16, d_in[11], d_in[12], d_out, d_in[0]);
}